// Round 1
// baseline (588.104 us; speedup 1.0000x reference)
//
#include <hip/hip_runtime.h>
#include <math.h>

#define Bn 32
#define Ln 512
#define Hn 256
#define NHn 4
#define DHn 64

// ---------------- generic tiled NT GEMM: C = A[M,K] * B[N,K]^T + bias (+ residual) ----------------
__global__ __launch_bounds__(256) void gemm_nt_bias(
    const float* __restrict__ A, int lda,
    const float* __restrict__ Bm, int ldb,
    const float* __restrict__ bias,
    const float* __restrict__ Res,   // nullable, row stride = ldc
    float* __restrict__ C, int ldc, int K)
{
    __shared__ __align__(16) float As[16][68];
    __shared__ __align__(16) float Bs[16][68];
    const int tid = threadIdx.x;
    const int tx = tid & 15, ty = tid >> 4;
    const int m0 = blockIdx.y * 64, n0 = blockIdx.x * 64;
    const int r = tid >> 2, cq = (tid & 3) * 4;
    const float* Ap = A + (size_t)(m0 + r) * lda + cq;
    const float* Bp = Bm + (size_t)(n0 + r) * ldb + cq;
    float acc[4][4];
#pragma unroll
    for (int i = 0; i < 4; ++i)
#pragma unroll
        for (int j = 0; j < 4; ++j) acc[i][j] = 0.f;

    for (int k0 = 0; k0 < K; k0 += 16) {
        float4 a4 = *(const float4*)(Ap + k0);
        float4 b4 = *(const float4*)(Bp + k0);
        __syncthreads();
        As[cq+0][r] = a4.x; As[cq+1][r] = a4.y; As[cq+2][r] = a4.z; As[cq+3][r] = a4.w;
        Bs[cq+0][r] = b4.x; Bs[cq+1][r] = b4.y; Bs[cq+2][r] = b4.z; Bs[cq+3][r] = b4.w;
        __syncthreads();
#pragma unroll
        for (int kk = 0; kk < 16; ++kk) {
            float4 av = *(const float4*)&As[kk][ty*4];
            float4 bv = *(const float4*)&Bs[kk][tx*4];
            float aa[4] = {av.x, av.y, av.z, av.w};
            float bb[4] = {bv.x, bv.y, bv.z, bv.w};
#pragma unroll
            for (int i = 0; i < 4; ++i)
#pragma unroll
                for (int j = 0; j < 4; ++j) acc[i][j] = fmaf(aa[i], bb[j], acc[i][j]);
        }
    }
#pragma unroll
    for (int i = 0; i < 4; ++i) {
        int m = m0 + ty*4 + i;
        int n = n0 + tx*4;
        float4 o;
        o.x = acc[i][0] + bias[n+0];
        o.y = acc[i][1] + bias[n+1];
        o.z = acc[i][2] + bias[n+2];
        o.w = acc[i][3] + bias[n+3];
        if (Res) {
            float4 rv = *(const float4*)(Res + (size_t)m * ldc + n);
            o.x += rv.x; o.y += rv.y; o.z += rv.z; o.w += rv.w;
        }
        *(float4*)(C + (size_t)m * ldc + n) = o;
    }
}

// ---------------- time-decay gate: gate[b,i,j] = sigmoid(tow1*decay + tow2*tanh(tq_i . x_j) + tob) ----
__global__ __launch_bounds__(256) void gate_kernel(
    const float* __restrict__ TQ, const float* __restrict__ X,
    const float* __restrict__ tseq,
    const float* __restrict__ tw1, const float* __restrict__ tb1,
    const float* __restrict__ tow1, const float* __restrict__ tow2,
    const float* __restrict__ tob,
    float* __restrict__ gate)
{
    __shared__ __align__(16) float As[16][68];
    __shared__ __align__(16) float Bs[16][68];
    const int tid = threadIdx.x;
    const int tx = tid & 15, ty = tid >> 4;
    const int b = blockIdx.z;
    const int m0 = blockIdx.y * 64, n0 = blockIdx.x * 64;
    const int r = tid >> 2, cq = (tid & 3) * 4;
    const float* Ap = TQ + (size_t)b * Ln * Hn + (size_t)(m0 + r) * Hn + cq;
    const float* Bp = X  + (size_t)b * Ln * Hn + (size_t)(n0 + r) * Hn + cq;
    float acc[4][4];
#pragma unroll
    for (int i = 0; i < 4; ++i)
#pragma unroll
        for (int j = 0; j < 4; ++j) acc[i][j] = 0.f;

    for (int k0 = 0; k0 < Hn; k0 += 16) {
        float4 a4 = *(const float4*)(Ap + k0);
        float4 b4 = *(const float4*)(Bp + k0);
        __syncthreads();
        As[cq+0][r] = a4.x; As[cq+1][r] = a4.y; As[cq+2][r] = a4.z; As[cq+3][r] = a4.w;
        Bs[cq+0][r] = b4.x; Bs[cq+1][r] = b4.y; Bs[cq+2][r] = b4.z; Bs[cq+3][r] = b4.w;
        __syncthreads();
#pragma unroll
        for (int kk = 0; kk < 16; ++kk) {
            float4 av = *(const float4*)&As[kk][ty*4];
            float4 bv = *(const float4*)&Bs[kk][tx*4];
            float aa[4] = {av.x, av.y, av.z, av.w};
            float bb[4] = {bv.x, bv.y, bv.z, bv.w};
#pragma unroll
            for (int i = 0; i < 4; ++i)
#pragma unroll
                for (int j = 0; j < 4; ++j) acc[i][j] = fmaf(aa[i], bb[j], acc[i][j]);
        }
    }
    const float* ts = tseq + (size_t)b * Ln;
#pragma unroll
    for (int i = 0; i < 4; ++i) {
        int irow = m0 + ty*4 + i;
        int jc = n0 + tx*4;
        float ti = ts[irow];
        size_t idx = (size_t)irow * Ln + jc;
        float4 w1 = *(const float4*)(tw1 + idx);
        float4 b1 = *(const float4*)(tb1 + idx);
        float4 o1 = *(const float4*)(tow1 + idx);
        float4 o2 = *(const float4*)(tow2 + idx);
        float4 ob = *(const float4*)(tob + idx);
        float w1a[4] = {w1.x,w1.y,w1.z,w1.w}, b1a[4] = {b1.x,b1.y,b1.z,b1.w};
        float o1a[4] = {o1.x,o1.y,o1.z,o1.w}, o2a[4] = {o2.x,o2.y,o2.z,o2.w};
        float oba[4] = {ob.x,ob.y,ob.z,ob.w};
        float out[4];
#pragma unroll
        for (int j = 0; j < 4; ++j) {
            float tj = ts[jc + j];
            float dt = fabsf(ti - tj);
            float decay = tanhf(log1pf(dt) * w1a[j] + b1a[j]);
            float tqk = tanhf(acc[i][j]);
            float dg = o1a[j] * decay + o2a[j] * tqk + oba[j];
            out[j] = 1.f / (1.f + __expf(-dg));
        }
        float4 ov = {out[0], out[1], out[2], out[3]};
        *(float4*)(gate + (size_t)b * Ln * Ln + idx) = ov;
    }
}

// ---------------- flash attention with gate: 32-q tile, 64-k tiles, online softmax --------------
__global__ __launch_bounds__(256) void flash_attn(
    const float* __restrict__ Q, const float* __restrict__ Kw,
    const float* __restrict__ Vw, const float* __restrict__ gate,
    const float* __restrict__ mask, float* __restrict__ ctx)
{
    __shared__ __align__(16) float Qt[32][68];   // [q][d]
    __shared__ __align__(16) float KtT[64][68];  // [d][k]
    __shared__ __align__(16) float Vt[64][68];   // [k][d]
    __shared__ __align__(16) float Pt[32][69];   // [q][k]  (odd-ish pad, scalar access)
    const int tid = threadIdx.x;
    const int blk = blockIdx.x;
    const int qt = blk & 15;
    const int h  = (blk >> 4) & 3;
    const int b  = blk >> 6;
    const int q0 = qt * 32;
    const float* qptr = Q  + (size_t)b * Ln * Hn + h * DHn;
    const float* kptr = Kw + (size_t)b * Ln * Hn + h * DHn;
    const float* vptr = Vw + (size_t)b * Ln * Hn + h * DHn;
    const int q  = tid >> 3;      // 0..31
    const int sl = tid & 7;
    const int kb = sl * 8;        // k sub-range this thread scores
    const int db = sl * 8;        // d sub-range this thread accumulates

    // stage Q tile
    {
        int rr = tid >> 3;
        int cc = (tid & 7) * 8;
        const float* src = qptr + (size_t)(q0 + rr) * Hn + cc;
        float4 x0 = *(const float4*)src;
        float4 x1 = *(const float4*)(src + 4);
        Qt[rr][cc+0] = x0.x; Qt[rr][cc+1] = x0.y; Qt[rr][cc+2] = x0.z; Qt[rr][cc+3] = x0.w;
        Qt[rr][cc+4] = x1.x; Qt[rr][cc+5] = x1.y; Qt[rr][cc+6] = x1.z; Qt[rr][cc+7] = x1.w;
    }

    const float* grow = gate + ((size_t)b * Ln + (q0 + q)) * Ln;
    const float* mrow = mask + ((size_t)b * Ln + (q0 + q)) * Ln;

    float m_run = -INFINITY, l_run = 0.f;
    float acc[8] = {0.f,0.f,0.f,0.f,0.f,0.f,0.f,0.f};

    for (int k0 = 0; k0 < Ln; k0 += 64) {
        __syncthreads();   // protect KtT/Vt/Pt (prev PV readers done)
        {
            int rr = tid >> 2;            // k row 0..63
            int cb = (tid & 3) * 16;      // d col base
            const float* ks = kptr + (size_t)(k0 + rr) * Hn + cb;
            const float* vs = vptr + (size_t)(k0 + rr) * Hn + cb;
#pragma unroll
            for (int u = 0; u < 4; ++u) {
                float4 k4 = *(const float4*)(ks + u*4);
                int cc = cb + u*4;
                KtT[cc+0][rr] = k4.x; KtT[cc+1][rr] = k4.y;
                KtT[cc+2][rr] = k4.z; KtT[cc+3][rr] = k4.w;
            }
#pragma unroll
            for (int u = 0; u < 4; ++u) {
                float4 v4 = *(const float4*)(vs + u*4);
                *(float4*)&Vt[rr][cb + u*4] = v4;
            }
        }
        __syncthreads();

        // scores for (q, k0+kb .. k0+kb+7)
        float s[8] = {0.f,0.f,0.f,0.f,0.f,0.f,0.f,0.f};
#pragma unroll 8
        for (int d = 0; d < 64; ++d) {
            float qv = Qt[q][d];
            float4 ka = *(const float4*)&KtT[d][kb];
            float4 kc = *(const float4*)&KtT[d][kb+4];
            s[0] = fmaf(qv, ka.x, s[0]); s[1] = fmaf(qv, ka.y, s[1]);
            s[2] = fmaf(qv, ka.z, s[2]); s[3] = fmaf(qv, ka.w, s[3]);
            s[4] = fmaf(qv, kc.x, s[4]); s[5] = fmaf(qv, kc.y, s[5]);
            s[6] = fmaf(qv, kc.z, s[6]); s[7] = fmaf(qv, kc.w, s[7]);
        }
        float4 g0 = *(const float4*)(grow + k0 + kb);
        float4 g1 = *(const float4*)(grow + k0 + kb + 4);
        float4 ma = *(const float4*)(mrow + k0 + kb);
        float4 mb = *(const float4*)(mrow + k0 + kb + 4);
        s[0] = s[0]*g0.x*0.125f + ma.x; s[1] = s[1]*g0.y*0.125f + ma.y;
        s[2] = s[2]*g0.z*0.125f + ma.z; s[3] = s[3]*g0.w*0.125f + ma.w;
        s[4] = s[4]*g1.x*0.125f + mb.x; s[5] = s[5]*g1.y*0.125f + mb.y;
        s[6] = s[6]*g1.z*0.125f + mb.z; s[7] = s[7]*g1.w*0.125f + mb.w;

        float tmax = s[0];
#pragma unroll
        for (int u = 1; u < 8; ++u) tmax = fmaxf(tmax, s[u]);
#pragma unroll
        for (int off = 1; off < 8; off <<= 1) tmax = fmaxf(tmax, __shfl_xor(tmax, off, 64));
        float m_new = fmaxf(m_run, tmax);
        float alpha = __expf(m_run - m_new);   // -inf first iter -> 0
        float p[8]; float ps = 0.f;
#pragma unroll
        for (int u = 0; u < 8; ++u) { p[u] = __expf(s[u] - m_new); ps += p[u]; }
#pragma unroll
        for (int off = 1; off < 8; off <<= 1) ps += __shfl_xor(ps, off, 64);
        l_run = l_run * alpha + ps;
        m_run = m_new;
#pragma unroll
        for (int u = 0; u < 8; ++u) acc[u] *= alpha;
#pragma unroll
        for (int u = 0; u < 8; ++u) Pt[q][kb + u] = p[u];
        __syncthreads();

        // PV
#pragma unroll 4
        for (int k = 0; k < 64; ++k) {
            float pv = Pt[q][k];
            float4 v0 = *(const float4*)&Vt[k][db];
            float4 v1 = *(const float4*)&Vt[k][db+4];
            acc[0] = fmaf(pv, v0.x, acc[0]); acc[1] = fmaf(pv, v0.y, acc[1]);
            acc[2] = fmaf(pv, v0.z, acc[2]); acc[3] = fmaf(pv, v0.w, acc[3]);
            acc[4] = fmaf(pv, v1.x, acc[4]); acc[5] = fmaf(pv, v1.y, acc[5]);
            acc[6] = fmaf(pv, v1.z, acc[6]); acc[7] = fmaf(pv, v1.w, acc[7]);
        }
    }

    float inv = 1.0f / l_run;
    float* obase = ctx + ((size_t)b * Ln + (q0 + q)) * Hn + h * DHn + db;
    float4 o0 = {acc[0]*inv, acc[1]*inv, acc[2]*inv, acc[3]*inv};
    float4 o1 = {acc[4]*inv, acc[5]*inv, acc[6]*inv, acc[7]*inv};
    *(float4*)obase = o0;
    *(float4*)(obase + 4) = o1;
}

// ---------------- in-place LayerNorm over H=256 (biased var, eps 1e-12) ----------------
__global__ __launch_bounds__(256) void ln_kernel(float* __restrict__ hs,
                                                 const float* __restrict__ g,
                                                 const float* __restrict__ bta)
{
    const int row = blockIdx.x, t = threadIdx.x;
    float v = hs[(size_t)row * Hn + t];
    float s1 = v, s2 = v * v;
#pragma unroll
    for (int off = 32; off > 0; off >>= 1) {
        s1 += __shfl_xor(s1, off, 64);
        s2 += __shfl_xor(s2, off, 64);
    }
    __shared__ float red[8];
    if ((t & 63) == 0) { red[t >> 6] = s1; red[4 + (t >> 6)] = s2; }
    __syncthreads();
    float sum = red[0] + red[1] + red[2] + red[3];
    float sq  = red[4] + red[5] + red[6] + red[7];
    float mu  = sum * (1.f / 256.f);
    float var = sq * (1.f / 256.f) - mu * mu;
    float rstd = rsqrtf(var + 1e-12f);
    hs[(size_t)row * Hn + t] = (v - mu) * rstd * g[t] + bta[t];
}

// ---------------- prediction head ----------------
__global__ __launch_bounds__(256) void pred_kernel(const float* __restrict__ hs,
                                                   const int* __restrict__ lens,
                                                   const float* __restrict__ Wt,
                                                   const float* __restrict__ bt,
                                                   float* __restrict__ pred)
{
    const int b = blockIdx.x, t = threadIdx.x;
    int len = lens[b];
    float e1 = hs[((size_t)b * Ln + (len - 1)) * Hn + t];
    float e2 = hs[((size_t)b * Ln + (len - 2)) * Hn + t];
    float v = e1 * Wt[t] + e2 * Wt[Hn + t];
#pragma unroll
    for (int off = 32; off > 0; off >>= 1) v += __shfl_xor(v, off, 64);
    __shared__ float ps[4];
    if ((t & 63) == 0) ps[t >> 6] = v;
    __syncthreads();
    if (t == 0) pred[b] = ps[0] + ps[1] + ps[2] + ps[3] + bt[0];
}

extern "C" void kernel_launch(void* const* d_in, const int* in_sizes, int n_in,
                              void* d_out, int out_size, void* d_ws, size_t ws_size,
                              hipStream_t stream) {
    (void)in_sizes; (void)n_in; (void)out_size; (void)ws_size;
    const float* x    = (const float*)d_in[0];
    const float* tseq = (const float*)d_in[1];
    const float* mask = (const float*)d_in[2];
    const int*   lens = (const int*)d_in[3];
    const float* Wq = (const float*)d_in[4];  const float* bq = (const float*)d_in[5];
    const float* Wk = (const float*)d_in[6];  const float* bk = (const float*)d_in[7];
    const float* Wv = (const float*)d_in[8];  const float* bv = (const float*)d_in[9];
    const float* Wd = (const float*)d_in[10]; const float* bd = (const float*)d_in[11];
    const float* ln_g = (const float*)d_in[12]; const float* ln_b = (const float*)d_in[13];
    const float* Wtq = (const float*)d_in[14]; const float* btq = (const float*)d_in[15];
    const float* tw1 = (const float*)d_in[16]; const float* tb1 = (const float*)d_in[17];
    const float* tow1 = (const float*)d_in[18]; const float* tow2 = (const float*)d_in[19];
    const float* tob = (const float*)d_in[20];
    const float* Wt = (const float*)d_in[21]; const float* bt = (const float*)d_in[22];

    float* ws = (float*)d_ws;
    const size_t NLH = (size_t)Bn * Ln * Hn;       // 4194304
    float* q_   = ws;
    float* k_   = ws + NLH;
    float* v_   = ws + 2 * NLH;
    float* tq_  = ws + 3 * NLH;
    float* gate = ws + 4 * NLH;                    // B*L*L = 8388608 floats
    float* ctx  = ws + 4 * NLH + (size_t)Bn * Ln * Ln;
    float* out  = (float*)d_out;                   // hs (in-place LN), then preds at +NLH

    dim3 blk(256);
    dim3 gproj(4, 256);   // N/64=4, M/64=256
    gemm_nt_bias<<<gproj, blk, 0, stream>>>(x, Hn, Wq, Hn, bq, nullptr, q_, Hn, Hn);
    gemm_nt_bias<<<gproj, blk, 0, stream>>>(x, Hn, Wk, Hn, bk, nullptr, k_, Hn, Hn);
    gemm_nt_bias<<<gproj, blk, 0, stream>>>(x, Hn, Wv, Hn, bv, nullptr, v_, Hn, Hn);
    gemm_nt_bias<<<gproj, blk, 0, stream>>>(x, Hn, Wtq, Hn, btq, nullptr, tq_, Hn, Hn);

    gate_kernel<<<dim3(8, 8, Bn), blk, 0, stream>>>(tq_, x, tseq, tw1, tb1, tow1, tow2, tob, gate);

    flash_attn<<<dim3(Bn * NHn * (Ln / 32)), blk, 0, stream>>>(q_, k_, v_, gate, mask, ctx);

    gemm_nt_bias<<<gproj, blk, 0, stream>>>(ctx, Hn, Wd, Hn, bd, x, out, Hn, Hn);

    ln_kernel<<<dim3(Bn * Ln), blk, 0, stream>>>(out, ln_g, ln_b);

    pred_kernel<<<dim3(Bn), blk, 0, stream>>>(out, lens, Wt, bt, out + NLH);
}

// Round 2
// 258.098 us; speedup vs baseline: 2.2786x; 2.2786x over previous
//
#include <hip/hip_runtime.h>
#include <math.h>

#define Bn 32
#define Ln 512
#define Hn 256
#define NHn 4
#define DHn 64

typedef __attribute__((ext_vector_type(8))) short bf16x8;
typedef __attribute__((ext_vector_type(4))) float f32x4;
typedef unsigned int uint32;

__device__ __forceinline__ short f2b(float f) {
    union { float f; uint32 u; } v; v.f = f;
    uint32 r = (v.u + 0x7FFFu + ((v.u >> 16) & 1u)) >> 16;
    return (short)r;
}
__device__ __forceinline__ float b2f(short h) {
    union { uint32 u; float f; } v; v.u = ((uint32)(unsigned short)h) << 16;
    return v.f;
}

// ---------------- fp32 -> bf16 conversion: x (B*L*H) and 5 weight mats ----------------
__global__ __launch_bounds__(256) void conv_kernel(
    const float* __restrict__ x,
    const float* __restrict__ Wq, const float* __restrict__ Wk,
    const float* __restrict__ Wv, const float* __restrict__ Wtq,
    const float* __restrict__ Wd,
    short* __restrict__ xb, short* __restrict__ wb)
{
    const size_t NLH = (size_t)Bn * Ln * Hn;
    size_t i4 = ((size_t)blockIdx.x * 256 + threadIdx.x) * 4;
    if (i4 < NLH) {
        float4 v = *(const float4*)(x + i4);
        short4 o; o.x = f2b(v.x); o.y = f2b(v.y); o.z = f2b(v.z); o.w = f2b(v.w);
        *(short4*)(xb + i4) = o;
    } else {
        size_t off = i4 - NLH;                 // < 5*65536
        int w = (int)(off >> 16);
        size_t wi = off & 65535;
        const float* src = (w == 0) ? Wq : (w == 1) ? Wk : (w == 2) ? Wv : (w == 3) ? Wtq : Wd;
        float4 v = *(const float4*)(src + wi);
        short4 o; o.x = f2b(v.x); o.y = f2b(v.y); o.z = f2b(v.z); o.w = f2b(v.w);
        *(short4*)(wb + off) = o;
    }
}

// ---------------- shared 64x64 bf16 MFMA NT-GEMM tile (K multiple of 64) ----------------
struct Acc { f32x4 t[4]; };

__device__ __forceinline__ void gemm_tile_64(
    const short* __restrict__ A,   // rows m0.., row stride K
    const short* __restrict__ Bm,  // rows n0.., row stride K
    int K, short* As, short* Bs, Acc& acc)
{
    const int tid = threadIdx.x;
    const int lane = tid & 63, w = tid >> 6;
    const int quad = lane >> 4, lm = lane & 15;
    const int srow = tid >> 3;   // 0..31
    const int slot = tid & 7;

    for (int k0 = 0; k0 < K; k0 += 64) {
        __syncthreads();
#pragma unroll
        for (int iss = 0; iss < 2; ++iss) {
            int r = srow + iss * 32;
            bf16x8 av = *(const bf16x8*)(A + (size_t)r * K + k0 + slot * 8);
            bf16x8 bv = *(const bf16x8*)(Bm + (size_t)r * K + k0 + slot * 8);
            *(bf16x8*)(As + r * 72 + slot * 8) = av;
            *(bf16x8*)(Bs + r * 72 + slot * 8) = bv;
        }
        __syncthreads();
#pragma unroll
        for (int ks = 0; ks < 2; ++ks) {
            bf16x8 a = *(const bf16x8*)(As + (w * 16 + lm) * 72 + ks * 32 + quad * 8);
#pragma unroll
            for (int kt = 0; kt < 4; ++kt) {
                bf16x8 b = *(const bf16x8*)(Bs + (kt * 16 + lm) * 72 + ks * 32 + quad * 8);
                acc.t[kt] = __builtin_amdgcn_mfma_f32_16x16x32_bf16(a, b, acc.t[kt], 0, 0, 0);
            }
        }
    }
}

// ---------------- fused QKV+TQ projection ----------------
__global__ __launch_bounds__(256) void proj_kernel(
    const short* __restrict__ xb, const short* __restrict__ wb,
    const float* __restrict__ bq, const float* __restrict__ bk,
    const float* __restrict__ bv, const float* __restrict__ btq,
    short* __restrict__ qb, short* __restrict__ kb,
    short* __restrict__ vb, short* __restrict__ tqb)
{
    __shared__ short As[64 * 72];
    __shared__ short Bs[64 * 72];
    const int tensor = blockIdx.x >> 2;
    const int ncol0 = (blockIdx.x & 3) * 64;
    const int m0 = blockIdx.y * 64;
    const short* A = xb + (size_t)m0 * Hn;
    const short* Bw = wb + (size_t)tensor * 65536 + (size_t)ncol0 * Hn;
    const float* bias = (tensor == 0) ? bq : (tensor == 1) ? bk : (tensor == 2) ? bv : btq;
    short* out = (tensor == 0) ? qb : (tensor == 1) ? kb : (tensor == 2) ? vb : tqb;

    Acc acc;
#pragma unroll
    for (int i = 0; i < 4; ++i) acc.t[i] = (f32x4){0.f, 0.f, 0.f, 0.f};
    gemm_tile_64(A, Bw, Hn, As, Bs, acc);

    const int lane = threadIdx.x & 63, w = threadIdx.x >> 6;
    const int quad = lane >> 4, lm = lane & 15;
#pragma unroll
    for (int kt = 0; kt < 4; ++kt) {
        int n = ncol0 + kt * 16 + lm;
        float bs = bias[n];
#pragma unroll
        for (int r = 0; r < 4; ++r) {
            int row = m0 + w * 16 + quad * 4 + r;
            out[(size_t)row * Hn + n] = f2b(acc.t[kt][r] + bs);
        }
    }
}

// ---------------- time-decay gate (bf16 out, includes /sqrt(DH)) ----------------
__global__ __launch_bounds__(256) void gate_kernel(
    const short* __restrict__ tqb, const short* __restrict__ xb,
    const float* __restrict__ tseq,
    const float* __restrict__ tw1, const float* __restrict__ tb1,
    const float* __restrict__ tow1, const float* __restrict__ tow2,
    const float* __restrict__ tob,
    short* __restrict__ gateb)
{
    __shared__ short As[64 * 72];
    __shared__ short Bs[64 * 72];
    const int b = blockIdx.z;
    const int m0 = blockIdx.y * 64, n0 = blockIdx.x * 64;
    const short* A = tqb + ((size_t)b * Ln + m0) * Hn;
    const short* Bw = xb + ((size_t)b * Ln + n0) * Hn;

    Acc acc;
#pragma unroll
    for (int i = 0; i < 4; ++i) acc.t[i] = (f32x4){0.f, 0.f, 0.f, 0.f};
    gemm_tile_64(A, Bw, Hn, As, Bs, acc);

    const int lane = threadIdx.x & 63, w = threadIdx.x >> 6;
    const int quad = lane >> 4, lm = lane & 15;
    const float* ts = tseq + (size_t)b * Ln;
    float ti[4];
#pragma unroll
    for (int r = 0; r < 4; ++r) ti[r] = ts[m0 + w * 16 + quad * 4 + r];
#pragma unroll
    for (int kt = 0; kt < 4; ++kt) {
        int j = n0 + kt * 16 + lm;
        float tj = ts[j];
#pragma unroll
        for (int r = 0; r < 4; ++r) {
            int i = m0 + w * 16 + quad * 4 + r;
            size_t ij = (size_t)i * Ln + j;
            float dec = tanhf(log1pf(fabsf(ti[r] - tj)) * tw1[ij] + tb1[ij]);
            float tqk = tanhf(acc.t[kt][r]);
            float dg = tow1[ij] * dec + tow2[ij] * tqk + tob[ij];
            float g = 0.125f / (1.f + __expf(-dg));
            gateb[(size_t)b * Ln * Ln + ij] = f2b(g);
        }
    }
}

// ---------------- flash attention, bf16 MFMA ----------------
__global__ __launch_bounds__(256) void flash_mfma(
    const short* __restrict__ qb, const short* __restrict__ kb,
    const short* __restrict__ vb, const short* __restrict__ gateb,
    const float* __restrict__ mask, short* __restrict__ ctxb)
{
    __shared__ short Ks[64 * 72];
    __shared__ short Vt[64 * 72];
    __shared__ short Ps[4 * 16 * 72];
    const int q0 = blockIdx.x * 64;
    const int h = blockIdx.y, b = blockIdx.z;
    const int tid = threadIdx.x;
    const int w = tid >> 6, lane = tid & 63;
    const int quad = lane >> 4, lm = lane & 15;

    bf16x8 qf0, qf1;
    {
        const short* qrow = qb + ((size_t)(b * Ln + q0 + w * 16 + lm)) * Hn + h * DHn;
        qf0 = *(const bf16x8*)(qrow + quad * 8);
        qf1 = *(const bf16x8*)(qrow + 32 + quad * 8);
    }

    f32x4 o[4];
#pragma unroll
    for (int i = 0; i < 4; ++i) o[i] = (f32x4){0.f, 0.f, 0.f, 0.f};
    float m_run[4] = {-INFINITY, -INFINITY, -INFINITY, -INFINITY};
    float l_run[4] = {0.f, 0.f, 0.f, 0.f};
    const short* gr_base = gateb + (size_t)b * Ln * Ln;
    const float* mk_base = mask + (size_t)b * Ln * Ln;
    const int qrow0 = q0 + w * 16 + quad * 4;

    for (int k0 = 0; k0 < Ln; k0 += 64) {
        __syncthreads();
        // stage K [key][d], stride-72 rows
        {
            int srow = tid >> 3, slot = tid & 7;
#pragma unroll
            for (int iss = 0; iss < 2; ++iss) {
                int r = srow + iss * 32;
                bf16x8 kv = *(const bf16x8*)(kb + ((size_t)(b * Ln + k0 + r)) * Hn + h * DHn + slot * 8);
                *(bf16x8*)(Ks + r * 72 + slot * 8) = kv;
            }
        }
        // stage V transposed: Vt[d][key]
        {
            int key = tid >> 2, dq = tid & 3;
            const short* vr = vb + ((size_t)(b * Ln + k0 + key)) * Hn + h * DHn + dq * 16;
            bf16x8 v0 = *(const bf16x8*)(vr);
            bf16x8 v1 = *(const bf16x8*)(vr + 8);
#pragma unroll
            for (int u = 0; u < 8; ++u) Vt[(dq * 16 + u) * 72 + key] = v0[u];
#pragma unroll
            for (int u = 0; u < 8; ++u) Vt[(dq * 16 + 8 + u) * 72 + key] = v1[u];
        }
        __syncthreads();

        // S = Q K^T
        f32x4 s[4];
#pragma unroll
        for (int kt = 0; kt < 4; ++kt) {
            s[kt] = (f32x4){0.f, 0.f, 0.f, 0.f};
            bf16x8 b0 = *(const bf16x8*)(Ks + (kt * 16 + lm) * 72 + quad * 8);
            s[kt] = __builtin_amdgcn_mfma_f32_16x16x32_bf16(qf0, b0, s[kt], 0, 0, 0);
            bf16x8 b1 = *(const bf16x8*)(Ks + (kt * 16 + lm) * 72 + 32 + quad * 8);
            s[kt] = __builtin_amdgcn_mfma_f32_16x16x32_bf16(qf1, b1, s[kt], 0, 0, 0);
        }

        // gate * s + mask, online softmax
        float mnew[4];
#pragma unroll
        for (int r = 0; r < 4; ++r) mnew[r] = m_run[r];
#pragma unroll
        for (int kt = 0; kt < 4; ++kt) {
            int col = k0 + kt * 16 + lm;
#pragma unroll
            for (int r = 0; r < 4; ++r) {
                float g = b2f(gr_base[(size_t)(qrow0 + r) * Ln + col]);
                float mv = mk_base[(size_t)(qrow0 + r) * Ln + col];
                float sv = s[kt][r] * g + mv;
                s[kt][r] = sv;
                mnew[r] = fmaxf(mnew[r], sv);
            }
        }
        float alpha[4], rsum[4];
#pragma unroll
        for (int r = 0; r < 4; ++r) {
#pragma unroll
            for (int off = 1; off < 16; off <<= 1)
                mnew[r] = fmaxf(mnew[r], __shfl_xor(mnew[r], off, 64));
            alpha[r] = __expf(m_run[r] - mnew[r]);
            m_run[r] = mnew[r];
            rsum[r] = 0.f;
        }
        float p[4][4];
#pragma unroll
        for (int kt = 0; kt < 4; ++kt)
#pragma unroll
            for (int r = 0; r < 4; ++r) {
                float pv = __expf(s[kt][r] - m_run[r]);
                p[kt][r] = pv;
                rsum[r] += pv;
            }
#pragma unroll
        for (int r = 0; r < 4; ++r) {
#pragma unroll
            for (int off = 1; off < 16; off <<= 1) rsum[r] += __shfl_xor(rsum[r], off, 64);
            l_run[r] = l_run[r] * alpha[r] + rsum[r];
#pragma unroll
            for (int ot = 0; ot < 4; ++ot) o[ot][r] *= alpha[r];
        }
        // P -> LDS (per-wave region), then PV
        short* pw = Ps + w * 16 * 72;
#pragma unroll
        for (int kt = 0; kt < 4; ++kt)
#pragma unroll
            for (int r = 0; r < 4; ++r)
                pw[(quad * 4 + r) * 72 + kt * 16 + lm] = f2b(p[kt][r]);

#pragma unroll
        for (int ks = 0; ks < 2; ++ks) {
            bf16x8 pa = *(const bf16x8*)(pw + lm * 72 + ks * 32 + quad * 8);
#pragma unroll
            for (int ot = 0; ot < 4; ++ot) {
                bf16x8 vv = *(const bf16x8*)(Vt + (ot * 16 + lm) * 72 + ks * 32 + quad * 8);
                o[ot] = __builtin_amdgcn_mfma_f32_16x16x32_bf16(pa, vv, o[ot], 0, 0, 0);
            }
        }
    }

    float inv[4];
#pragma unroll
    for (int r = 0; r < 4; ++r) inv[r] = 1.0f / l_run[r];
#pragma unroll
    for (int ot = 0; ot < 4; ++ot) {
        int d = h * DHn + ot * 16 + lm;
#pragma unroll
        for (int r = 0; r < 4; ++r) {
            int row = b * Ln + qrow0 + r;
            ctxb[(size_t)row * Hn + d] = f2b(o[ot][r] * inv[r]);
        }
    }
}

// ---------------- output projection + residual (fp32 out) ----------------
__global__ __launch_bounds__(256) void outproj_kernel(
    const short* __restrict__ ctxb, const short* __restrict__ wdb,
    const float* __restrict__ bd, const float* __restrict__ x,
    float* __restrict__ out)
{
    __shared__ short As[64 * 72];
    __shared__ short Bs[64 * 72];
    const int n0 = blockIdx.x * 64, m0 = blockIdx.y * 64;
    Acc acc;
#pragma unroll
    for (int i = 0; i < 4; ++i) acc.t[i] = (f32x4){0.f, 0.f, 0.f, 0.f};
    gemm_tile_64(ctxb + (size_t)m0 * Hn, wdb + (size_t)n0 * Hn, Hn, As, Bs, acc);

    const int lane = threadIdx.x & 63, w = threadIdx.x >> 6;
    const int quad = lane >> 4, lm = lane & 15;
#pragma unroll
    for (int kt = 0; kt < 4; ++kt) {
        int n = n0 + kt * 16 + lm;
        float bs = bd[n];
#pragma unroll
        for (int r = 0; r < 4; ++r) {
            int row = m0 + w * 16 + quad * 4 + r;
            out[(size_t)row * Hn + n] = acc.t[kt][r] + bs + x[(size_t)row * Hn + n];
        }
    }
}

// ---------------- in-place LayerNorm over H=256 ----------------
__global__ __launch_bounds__(256) void ln_kernel(float* __restrict__ hs,
                                                 const float* __restrict__ g,
                                                 const float* __restrict__ bta)
{
    const int row = blockIdx.x, t = threadIdx.x;
    float v = hs[(size_t)row * Hn + t];
    float s1 = v, s2 = v * v;
#pragma unroll
    for (int off = 32; off > 0; off >>= 1) {
        s1 += __shfl_xor(s1, off, 64);
        s2 += __shfl_xor(s2, off, 64);
    }
    __shared__ float red[8];
    if ((t & 63) == 0) { red[t >> 6] = s1; red[4 + (t >> 6)] = s2; }
    __syncthreads();
    float sum = red[0] + red[1] + red[2] + red[3];
    float sq  = red[4] + red[5] + red[6] + red[7];
    float mu  = sum * (1.f / 256.f);
    float var = sq * (1.f / 256.f) - mu * mu;
    float rstd = rsqrtf(var + 1e-12f);
    hs[(size_t)row * Hn + t] = (v - mu) * rstd * g[t] + bta[t];
}

// ---------------- prediction head ----------------
__global__ __launch_bounds__(256) void pred_kernel(const float* __restrict__ hs,
                                                   const int* __restrict__ lens,
                                                   const float* __restrict__ Wt,
                                                   const float* __restrict__ bt,
                                                   float* __restrict__ pred)
{
    const int b = blockIdx.x, t = threadIdx.x;
    int len = lens[b];
    float e1 = hs[((size_t)b * Ln + (len - 1)) * Hn + t];
    float e2 = hs[((size_t)b * Ln + (len - 2)) * Hn + t];
    float v = e1 * Wt[t] + e2 * Wt[Hn + t];
#pragma unroll
    for (int off = 32; off > 0; off >>= 1) v += __shfl_xor(v, off, 64);
    __shared__ float ps[4];
    if ((t & 63) == 0) ps[t >> 6] = v;
    __syncthreads();
    if (t == 0) pred[b] = ps[0] + ps[1] + ps[2] + ps[3] + bt[0];
}

extern "C" void kernel_launch(void* const* d_in, const int* in_sizes, int n_in,
                              void* d_out, int out_size, void* d_ws, size_t ws_size,
                              hipStream_t stream) {
    (void)in_sizes; (void)n_in; (void)out_size; (void)ws_size;
    const float* x    = (const float*)d_in[0];
    const float* tseq = (const float*)d_in[1];
    const float* mask = (const float*)d_in[2];
    const int*   lens = (const int*)d_in[3];
    const float* Wq = (const float*)d_in[4];  const float* bq = (const float*)d_in[5];
    const float* Wk = (const float*)d_in[6];  const float* bk = (const float*)d_in[7];
    const float* Wv = (const float*)d_in[8];  const float* bv = (const float*)d_in[9];
    const float* Wd = (const float*)d_in[10]; const float* bd = (const float*)d_in[11];
    const float* ln_g = (const float*)d_in[12]; const float* ln_b = (const float*)d_in[13];
    const float* Wtq = (const float*)d_in[14]; const float* btq = (const float*)d_in[15];
    const float* tw1 = (const float*)d_in[16]; const float* tb1 = (const float*)d_in[17];
    const float* tow1 = (const float*)d_in[18]; const float* tow2 = (const float*)d_in[19];
    const float* tob = (const float*)d_in[20];
    const float* Wt = (const float*)d_in[21]; const float* bt = (const float*)d_in[22];

    const size_t NLH = (size_t)Bn * Ln * Hn;   // 4194304
    short* ws = (short*)d_ws;
    short* xb    = ws;
    short* wb    = xb + NLH;                   // 5*65536
    short* qb    = wb + 5 * 65536;
    short* kb    = qb + NLH;
    short* vb    = kb + NLH;
    short* tqb   = vb + NLH;
    short* gateb = tqb + NLH;                  // B*L*L
    short* ctxb  = gateb + (size_t)Bn * Ln * Ln;
    float* out   = (float*)d_out;

    dim3 blk(256);
    conv_kernel<<<dim3(4416), blk, 0, stream>>>(x, Wq, Wk, Wv, Wtq, Wd, xb, wb);
    proj_kernel<<<dim3(16, 256), blk, 0, stream>>>(xb, wb, bq, bk, bv, btq, qb, kb, vb, tqb);
    gate_kernel<<<dim3(8, 8, Bn), blk, 0, stream>>>(tqb, xb, tseq, tw1, tb1, tow1, tow2, tob, gateb);
    flash_mfma<<<dim3(8, NHn, Bn), blk, 0, stream>>>(qb, kb, vb, gateb, mask, ctxb);
    outproj_kernel<<<dim3(4, 256), blk, 0, stream>>>(ctxb, wb + 4 * 65536, bd, x, out);
    ln_kernel<<<dim3(Bn * Ln), blk, 0, stream>>>(out, ln_g, ln_b);
    pred_kernel<<<dim3(Bn), blk, 0, stream>>>(out, lens, Wt, bt, out + NLH);
}

// Round 3
// 237.586 us; speedup vs baseline: 2.4753x; 1.0863x over previous
//
#include <hip/hip_runtime.h>
#include <math.h>

#define Bn 32
#define Ln 512
#define Hn 256
#define NHn 4
#define DHn 64

typedef __attribute__((ext_vector_type(8))) short bf16x8;
typedef __attribute__((ext_vector_type(4))) float f32x4;
typedef unsigned int uint32;

__device__ __forceinline__ short f2b(float f) {
    union { float f; uint32 u; } v; v.f = f;
    uint32 r = (v.u + 0x7FFFu + ((v.u >> 16) & 1u)) >> 16;
    return (short)r;
}
__device__ __forceinline__ float b2f(short h) {
    union { uint32 u; float f; } v; v.u = ((uint32)(unsigned short)h) << 16;
    return v.f;
}
// fast tanh: (e^{2x}-1)/(e^{2x}+1) = 1 - 2/(e^{2x}+1); exact limits at +-inf
__device__ __forceinline__ float fast_tanh(float x) {
    float e = __expf(2.f * x);
    return 1.f - 2.f * __builtin_amdgcn_rcpf(e + 1.f);
}
__device__ __forceinline__ float fast_sigmoid(float x) {
    return __builtin_amdgcn_rcpf(1.f + __expf(-x));
}

// ---------------- fp32 -> bf16 conversion: x (B*L*H) and 5 weight mats ----------------
__global__ __launch_bounds__(256) void conv_kernel(
    const float* __restrict__ x,
    const float* __restrict__ Wq, const float* __restrict__ Wk,
    const float* __restrict__ Wv, const float* __restrict__ Wtq,
    const float* __restrict__ Wd,
    short* __restrict__ xb, short* __restrict__ wb)
{
    const size_t NLH = (size_t)Bn * Ln * Hn;
    size_t i4 = ((size_t)blockIdx.x * 256 + threadIdx.x) * 4;
    if (i4 < NLH) {
        float4 v = *(const float4*)(x + i4);
        short4 o; o.x = f2b(v.x); o.y = f2b(v.y); o.z = f2b(v.z); o.w = f2b(v.w);
        *(short4*)(xb + i4) = o;
    } else {
        size_t off = i4 - NLH;                 // < 5*65536
        int w = (int)(off >> 16);
        size_t wi = off & 65535;
        const float* src = (w == 0) ? Wq : (w == 1) ? Wk : (w == 2) ? Wv : (w == 3) ? Wtq : Wd;
        float4 v = *(const float4*)(src + wi);
        short4 o; o.x = f2b(v.x); o.y = f2b(v.y); o.z = f2b(v.z); o.w = f2b(v.w);
        *(short4*)(wb + off) = o;
    }
}

// ---------------- shared 64x64 bf16 MFMA NT-GEMM tile (K multiple of 64) ----------------
struct Acc { f32x4 t[4]; };

__device__ __forceinline__ void gemm_tile_64(
    const short* __restrict__ A,   // rows m0.., row stride K
    const short* __restrict__ Bm,  // rows n0.., row stride K
    int K, short* As, short* Bs, Acc& acc)
{
    const int tid = threadIdx.x;
    const int lane = tid & 63, w = tid >> 6;
    const int quad = lane >> 4, lm = lane & 15;
    const int srow = tid >> 3;   // 0..31
    const int slot = tid & 7;

    for (int k0 = 0; k0 < K; k0 += 64) {
        __syncthreads();
#pragma unroll
        for (int iss = 0; iss < 2; ++iss) {
            int r = srow + iss * 32;
            bf16x8 av = *(const bf16x8*)(A + (size_t)r * K + k0 + slot * 8);
            bf16x8 bv = *(const bf16x8*)(Bm + (size_t)r * K + k0 + slot * 8);
            *(bf16x8*)(As + r * 72 + slot * 8) = av;
            *(bf16x8*)(Bs + r * 72 + slot * 8) = bv;
        }
        __syncthreads();
#pragma unroll
        for (int ks = 0; ks < 2; ++ks) {
            bf16x8 a = *(const bf16x8*)(As + (w * 16 + lm) * 72 + ks * 32 + quad * 8);
#pragma unroll
            for (int kt = 0; kt < 4; ++kt) {
                bf16x8 b = *(const bf16x8*)(Bs + (kt * 16 + lm) * 72 + ks * 32 + quad * 8);
                acc.t[kt] = __builtin_amdgcn_mfma_f32_16x16x32_bf16(a, b, acc.t[kt], 0, 0, 0);
            }
        }
    }
}

// ---------------- fused QKV+TQ projection ----------------
__global__ __launch_bounds__(256) void proj_kernel(
    const short* __restrict__ xb, const short* __restrict__ wb,
    const float* __restrict__ bq, const float* __restrict__ bk,
    const float* __restrict__ bv, const float* __restrict__ btq,
    short* __restrict__ qb, short* __restrict__ kb,
    short* __restrict__ vb, short* __restrict__ tqb)
{
    __shared__ short As[64 * 72];
    __shared__ short Bs[64 * 72];
    const int tensor = blockIdx.x >> 2;
    const int ncol0 = (blockIdx.x & 3) * 64;
    const int m0 = blockIdx.y * 64;
    const short* A = xb + (size_t)m0 * Hn;
    const short* Bw = wb + (size_t)tensor * 65536 + (size_t)ncol0 * Hn;
    const float* bias = (tensor == 0) ? bq : (tensor == 1) ? bk : (tensor == 2) ? bv : btq;
    short* out = (tensor == 0) ? qb : (tensor == 1) ? kb : (tensor == 2) ? vb : tqb;

    Acc acc;
#pragma unroll
    for (int i = 0; i < 4; ++i) acc.t[i] = (f32x4){0.f, 0.f, 0.f, 0.f};
    gemm_tile_64(A, Bw, Hn, As, Bs, acc);

    const int lane = threadIdx.x & 63, w = threadIdx.x >> 6;
    const int quad = lane >> 4, lm = lane & 15;
#pragma unroll
    for (int kt = 0; kt < 4; ++kt) {
        int n = ncol0 + kt * 16 + lm;
        float bs = bias[n];
#pragma unroll
        for (int r = 0; r < 4; ++r) {
            int row = m0 + w * 16 + quad * 4 + r;
            out[(size_t)row * Hn + n] = f2b(acc.t[kt][r] + bs);
        }
    }
}

// ---------------- time-decay gate (bf16 out, includes /sqrt(DH)) ----------------
__global__ __launch_bounds__(256) void gate_kernel(
    const short* __restrict__ tqb, const short* __restrict__ xb,
    const float* __restrict__ tseq,
    const float* __restrict__ tw1, const float* __restrict__ tb1,
    const float* __restrict__ tow1, const float* __restrict__ tow2,
    const float* __restrict__ tob,
    short* __restrict__ gateb)
{
    __shared__ short As[64 * 72];
    __shared__ short Bs[64 * 72];
    const int b = blockIdx.z;
    const int m0 = blockIdx.y * 64, n0 = blockIdx.x * 64;
    const short* A = tqb + ((size_t)b * Ln + m0) * Hn;
    const short* Bw = xb + ((size_t)b * Ln + n0) * Hn;

    Acc acc;
#pragma unroll
    for (int i = 0; i < 4; ++i) acc.t[i] = (f32x4){0.f, 0.f, 0.f, 0.f};
    gemm_tile_64(A, Bw, Hn, As, Bs, acc);

    const int lane = threadIdx.x & 63, w = threadIdx.x >> 6;
    const int quad = lane >> 4, lm = lane & 15;
    const float* ts = tseq + (size_t)b * Ln;
    float ti[4];
#pragma unroll
    for (int r = 0; r < 4; ++r) ti[r] = ts[m0 + w * 16 + quad * 4 + r];
#pragma unroll
    for (int kt = 0; kt < 4; ++kt) {
        int j = n0 + kt * 16 + lm;
        float tj = ts[j];
#pragma unroll
        for (int r = 0; r < 4; ++r) {
            int i = m0 + w * 16 + quad * 4 + r;
            size_t ij = (size_t)i * Ln + j;
            float lg = __logf(1.f + fabsf(ti[r] - tj));
            float dec = fast_tanh(lg * tw1[ij] + tb1[ij]);
            float tqk = fast_tanh(acc.t[kt][r]);
            float dg = tow1[ij] * dec + tow2[ij] * tqk + tob[ij];
            float g = 0.125f * fast_sigmoid(dg);
            gateb[(size_t)b * Ln * Ln + ij] = f2b(g);
        }
    }
}

// ---------------- flash attention, bf16 MFMA ----------------
__global__ __launch_bounds__(256) void flash_mfma(
    const short* __restrict__ qb, const short* __restrict__ kb,
    const short* __restrict__ vb, const short* __restrict__ gateb,
    const float* __restrict__ mask, short* __restrict__ ctxb)
{
    __shared__ short Ks[64 * 72];
    __shared__ short Vt[64 * 72];
    __shared__ short Ps[4 * 16 * 72];
    const int q0 = blockIdx.x * 64;
    const int h = blockIdx.y, b = blockIdx.z;
    const int tid = threadIdx.x;
    const int w = tid >> 6, lane = tid & 63;
    const int quad = lane >> 4, lm = lane & 15;

    bf16x8 qf0, qf1;
    {
        const short* qrow = qb + ((size_t)(b * Ln + q0 + w * 16 + lm)) * Hn + h * DHn;
        qf0 = *(const bf16x8*)(qrow + quad * 8);
        qf1 = *(const bf16x8*)(qrow + 32 + quad * 8);
    }

    f32x4 o[4];
#pragma unroll
    for (int i = 0; i < 4; ++i) o[i] = (f32x4){0.f, 0.f, 0.f, 0.f};
    float m_run[4] = {-INFINITY, -INFINITY, -INFINITY, -INFINITY};
    float l_run[4] = {0.f, 0.f, 0.f, 0.f};
    const short* gr_base = gateb + (size_t)b * Ln * Ln;
    const float* mk_base = mask + (size_t)b * Ln * Ln;
    const int qrow0 = q0 + w * 16 + quad * 4;

    for (int k0 = 0; k0 < Ln; k0 += 64) {
        __syncthreads();
        // stage K [key][d], stride-72 rows
        {
            int srow = tid >> 3, slot = tid & 7;
#pragma unroll
            for (int iss = 0; iss < 2; ++iss) {
                int r = srow + iss * 32;
                bf16x8 kv = *(const bf16x8*)(kb + ((size_t)(b * Ln + k0 + r)) * Hn + h * DHn + slot * 8);
                *(bf16x8*)(Ks + r * 72 + slot * 8) = kv;
            }
        }
        // stage V transposed: Vt[d][key]
        {
            int key = tid >> 2, dq = tid & 3;
            const short* vr = vb + ((size_t)(b * Ln + k0 + key)) * Hn + h * DHn + dq * 16;
            bf16x8 v0 = *(const bf16x8*)(vr);
            bf16x8 v1 = *(const bf16x8*)(vr + 8);
#pragma unroll
            for (int u = 0; u < 8; ++u) Vt[(dq * 16 + u) * 72 + key] = v0[u];
#pragma unroll
            for (int u = 0; u < 8; ++u) Vt[(dq * 16 + 8 + u) * 72 + key] = v1[u];
        }
        __syncthreads();

        // S = Q K^T
        f32x4 s[4];
#pragma unroll
        for (int kt = 0; kt < 4; ++kt) {
            s[kt] = (f32x4){0.f, 0.f, 0.f, 0.f};
            bf16x8 b0 = *(const bf16x8*)(Ks + (kt * 16 + lm) * 72 + quad * 8);
            s[kt] = __builtin_amdgcn_mfma_f32_16x16x32_bf16(qf0, b0, s[kt], 0, 0, 0);
            bf16x8 b1 = *(const bf16x8*)(Ks + (kt * 16 + lm) * 72 + 32 + quad * 8);
            s[kt] = __builtin_amdgcn_mfma_f32_16x16x32_bf16(qf1, b1, s[kt], 0, 0, 0);
        }

        // gate * s + mask, online softmax
        float mnew[4];
#pragma unroll
        for (int r = 0; r < 4; ++r) mnew[r] = m_run[r];
#pragma unroll
        for (int kt = 0; kt < 4; ++kt) {
            int col = k0 + kt * 16 + lm;
#pragma unroll
            for (int r = 0; r < 4; ++r) {
                float g = b2f(gr_base[(size_t)(qrow0 + r) * Ln + col]);
                float mv = mk_base[(size_t)(qrow0 + r) * Ln + col];
                float sv = s[kt][r] * g + mv;
                s[kt][r] = sv;
                mnew[r] = fmaxf(mnew[r], sv);
            }
        }
        float alpha[4], rsum[4];
#pragma unroll
        for (int r = 0; r < 4; ++r) {
#pragma unroll
            for (int off = 1; off < 16; off <<= 1)
                mnew[r] = fmaxf(mnew[r], __shfl_xor(mnew[r], off, 64));
            alpha[r] = __expf(m_run[r] - mnew[r]);
            m_run[r] = mnew[r];
            rsum[r] = 0.f;
        }
        float p[4][4];
#pragma unroll
        for (int kt = 0; kt < 4; ++kt)
#pragma unroll
            for (int r = 0; r < 4; ++r) {
                float pv = __expf(s[kt][r] - m_run[r]);
                p[kt][r] = pv;
                rsum[r] += pv;
            }
#pragma unroll
        for (int r = 0; r < 4; ++r) {
#pragma unroll
            for (int off = 1; off < 16; off <<= 1) rsum[r] += __shfl_xor(rsum[r], off, 64);
            l_run[r] = l_run[r] * alpha[r] + rsum[r];
#pragma unroll
            for (int ot = 0; ot < 4; ++ot) o[ot][r] *= alpha[r];
        }
        // P -> LDS (per-wave region), then PV
        short* pw = Ps + w * 16 * 72;
#pragma unroll
        for (int kt = 0; kt < 4; ++kt)
#pragma unroll
            for (int r = 0; r < 4; ++r)
                pw[(quad * 4 + r) * 72 + kt * 16 + lm] = f2b(p[kt][r]);

#pragma unroll
        for (int ks = 0; ks < 2; ++ks) {
            bf16x8 pa = *(const bf16x8*)(pw + lm * 72 + ks * 32 + quad * 8);
#pragma unroll
            for (int ot = 0; ot < 4; ++ot) {
                bf16x8 vv = *(const bf16x8*)(Vt + (ot * 16 + lm) * 72 + ks * 32 + quad * 8);
                o[ot] = __builtin_amdgcn_mfma_f32_16x16x32_bf16(pa, vv, o[ot], 0, 0, 0);
            }
        }
    }

    float inv[4];
#pragma unroll
    for (int r = 0; r < 4; ++r) inv[r] = 1.0f / l_run[r];
#pragma unroll
    for (int ot = 0; ot < 4; ++ot) {
        int d = h * DHn + ot * 16 + lm;
#pragma unroll
        for (int r = 0; r < 4; ++r) {
            int row = b * Ln + qrow0 + r;
            ctxb[(size_t)row * Hn + d] = f2b(o[ot][r] * inv[r]);
        }
    }
}

// ---------------- output projection + residual (fp32 out) ----------------
__global__ __launch_bounds__(256) void outproj_kernel(
    const short* __restrict__ ctxb, const short* __restrict__ wdb,
    const float* __restrict__ bd, const float* __restrict__ x,
    float* __restrict__ out)
{
    __shared__ short As[64 * 72];
    __shared__ short Bs[64 * 72];
    const int n0 = blockIdx.x * 64, m0 = blockIdx.y * 64;
    Acc acc;
#pragma unroll
    for (int i = 0; i < 4; ++i) acc.t[i] = (f32x4){0.f, 0.f, 0.f, 0.f};
    gemm_tile_64(ctxb + (size_t)m0 * Hn, wdb + (size_t)n0 * Hn, Hn, As, Bs, acc);

    const int lane = threadIdx.x & 63, w = threadIdx.x >> 6;
    const int quad = lane >> 4, lm = lane & 15;
#pragma unroll
    for (int kt = 0; kt < 4; ++kt) {
        int n = n0 + kt * 16 + lm;
        float bs = bd[n];
#pragma unroll
        for (int r = 0; r < 4; ++r) {
            int row = m0 + w * 16 + quad * 4 + r;
            out[(size_t)row * Hn + n] = acc.t[kt][r] + bs + x[(size_t)row * Hn + n];
        }
    }
}

// ---------------- in-place LayerNorm over H=256 ----------------
__global__ __launch_bounds__(256) void ln_kernel(float* __restrict__ hs,
                                                 const float* __restrict__ g,
                                                 const float* __restrict__ bta)
{
    const int row = blockIdx.x, t = threadIdx.x;
    float v = hs[(size_t)row * Hn + t];
    float s1 = v, s2 = v * v;
#pragma unroll
    for (int off = 32; off > 0; off >>= 1) {
        s1 += __shfl_xor(s1, off, 64);
        s2 += __shfl_xor(s2, off, 64);
    }
    __shared__ float red[8];
    if ((t & 63) == 0) { red[t >> 6] = s1; red[4 + (t >> 6)] = s2; }
    __syncthreads();
    float sum = red[0] + red[1] + red[2] + red[3];
    float sq  = red[4] + red[5] + red[6] + red[7];
    float mu  = sum * (1.f / 256.f);
    float var = sq * (1.f / 256.f) - mu * mu;
    float rstd = rsqrtf(var + 1e-12f);
    hs[(size_t)row * Hn + t] = (v - mu) * rstd * g[t] + bta[t];
}

// ---------------- prediction head ----------------
__global__ __launch_bounds__(256) void pred_kernel(const float* __restrict__ hs,
                                                   const int* __restrict__ lens,
                                                   const float* __restrict__ Wt,
                                                   const float* __restrict__ bt,
                                                   float* __restrict__ pred)
{
    const int b = blockIdx.x, t = threadIdx.x;
    int len = lens[b];
    float e1 = hs[((size_t)b * Ln + (len - 1)) * Hn + t];
    float e2 = hs[((size_t)b * Ln + (len - 2)) * Hn + t];
    float v = e1 * Wt[t] + e2 * Wt[Hn + t];
#pragma unroll
    for (int off = 32; off > 0; off >>= 1) v += __shfl_xor(v, off, 64);
    __shared__ float ps[4];
    if ((t & 63) == 0) ps[t >> 6] = v;
    __syncthreads();
    if (t == 0) pred[b] = ps[0] + ps[1] + ps[2] + ps[3] + bt[0];
}

extern "C" void kernel_launch(void* const* d_in, const int* in_sizes, int n_in,
                              void* d_out, int out_size, void* d_ws, size_t ws_size,
                              hipStream_t stream) {
    (void)in_sizes; (void)n_in; (void)out_size; (void)ws_size;
    const float* x    = (const float*)d_in[0];
    const float* tseq = (const float*)d_in[1];
    const float* mask = (const float*)d_in[2];
    const int*   lens = (const int*)d_in[3];
    const float* Wq = (const float*)d_in[4];  const float* bq = (const float*)d_in[5];
    const float* Wk = (const float*)d_in[6];  const float* bk = (const float*)d_in[7];
    const float* Wv = (const float*)d_in[8];  const float* bv = (const float*)d_in[9];
    const float* Wd = (const float*)d_in[10]; const float* bd = (const float*)d_in[11];
    const float* ln_g = (const float*)d_in[12]; const float* ln_b = (const float*)d_in[13];
    const float* Wtq = (const float*)d_in[14]; const float* btq = (const float*)d_in[15];
    const float* tw1 = (const float*)d_in[16]; const float* tb1 = (const float*)d_in[17];
    const float* tow1 = (const float*)d_in[18]; const float* tow2 = (const float*)d_in[19];
    const float* tob = (const float*)d_in[20];
    const float* Wt = (const float*)d_in[21]; const float* bt = (const float*)d_in[22];

    const size_t NLH = (size_t)Bn * Ln * Hn;   // 4194304
    short* ws = (short*)d_ws;
    short* xb    = ws;
    short* wb    = xb + NLH;                   // 5*65536
    short* qb    = wb + 5 * 65536;
    short* kb    = qb + NLH;
    short* vb    = kb + NLH;
    short* tqb   = vb + NLH;
    short* gateb = tqb + NLH;                  // B*L*L
    short* ctxb  = gateb + (size_t)Bn * Ln * Ln;
    float* out   = (float*)d_out;

    dim3 blk(256);
    conv_kernel<<<dim3(4416), blk, 0, stream>>>(x, Wq, Wk, Wv, Wtq, Wd, xb, wb);
    proj_kernel<<<dim3(16, 256), blk, 0, stream>>>(xb, wb, bq, bk, bv, btq, qb, kb, vb, tqb);
    gate_kernel<<<dim3(8, 8, Bn), blk, 0, stream>>>(tqb, xb, tseq, tw1, tb1, tow1, tow2, tob, gateb);
    flash_mfma<<<dim3(8, NHn, Bn), blk, 0, stream>>>(qb, kb, vb, gateb, mask, ctxb);
    outproj_kernel<<<dim3(4, 256), blk, 0, stream>>>(ctxb, wb + 4 * 65536, bd, x, out);
    ln_kernel<<<dim3(Bn * Ln), blk, 0, stream>>>(out, ln_g, ln_b);
    pred_kernel<<<dim3(Bn), blk, 0, stream>>>(out, lens, Wt, bt, out + NLH);
}